// Round 16
// baseline (93.268 us; speedup 1.0000x reference)
//
#include <hip/hip_runtime.h>
#include <math.h>

// MAM "FullyConnected": C[n,m] = max_k(x[n,k]*w[m,k]) + min_k(...) + bias[m]
// plus argmax/argmin (first occurrence). N=1024, M=512, K=512, f32.
// d_out (read back as f32): C | argmax | argmin, each N*M.
//
// Round 16: intra-wave software pipeline. All prior rounds: wall = LDS-pipe
// time + VALU time SUMMED (zero overlap) because the 128-VGPR budget could
// not hold two groups of operands -> loads never in flight during compute.
// Now: 256-thr blocks, launch_bounds(256,2) -> 256-VGPR budget; w[32][516]
// staged once (66KB, one barrier); x from global/L1; explicit A/B named
// register sets: load B(g+1) / compute A(g) / load A(g+2) / compute B(g+1).

constexpr int NTOT = 1024;
constexpr int MTOT = 512;
constexpr int KTOT = 512;
constexpr int BN = 32;
constexpr int BM = 32;
constexpr int G  = 16;        // tournament group size
constexpr int LDSPW = 516;    // 512+4: rows 16B-aligned; 4c-mod-32 banks -> 2-way only (free)

__device__ __forceinline__ float max3f(float a, float b, float c) {
  float d; asm("v_max3_f32 %0, %1, %2, %3" : "=v"(d) : "v"(a), "v"(b), "v"(c)); return d;
}
__device__ __forceinline__ float min3f(float a, float b, float c) {
  float d; asm("v_min3_f32 %0, %1, %2, %3" : "=v"(d) : "v"(a), "v"(b), "v"(c)); return d;
}
__device__ __forceinline__ float fmul0(float a, float b) {  // a*b on the 2-cy FMA pipe
  float d; asm("v_fma_f32 %0, %1, %2, 0" : "=v"(d) : "v"(a), "v"(b)); return d;
}
__device__ __forceinline__ float4 f4mul(float4 a, float4 b) {
  return make_float4(fmul0(a.x, b.x), fmul0(a.y, b.y), fmul0(a.z, b.z), fmul0(a.w, b.w));
}

__device__ __forceinline__ void tree16(const float4& q0, const float4& q1,
                                       const float4& q2, const float4& q3,
                                       float& M, float& m) {
  M = fmaxf(max3f(max3f(q0.x, q0.y, q0.z), max3f(q0.w, q1.x, q1.y),
                  max3f(q1.z, q1.w, q2.x)),
            max3f(max3f(q2.y, q2.z, q2.w), q3.x, max3f(q3.y, q3.z, q3.w)));
  m = fminf(min3f(min3f(q0.x, q0.y, q0.z), min3f(q0.w, q1.x, q1.y),
                  min3f(q1.z, q1.w, q2.x)),
            min3f(min3f(q2.y, q2.z, q2.w), q3.x, min3f(q3.y, q3.z, q3.w)));
}

// value tree over one 16-k group for one cell + running group update.
// strict > / < : first group attaining the extremum wins (first occurrence).
#define CELL(S, A0, A1, A2, A3, B0, B1, B2, B3)                              \
  {                                                                          \
    const float4 q0 = f4mul(A0, B0), q1 = f4mul(A1, B1);                     \
    const float4 q2 = f4mul(A2, B2), q3 = f4mul(A3, B3);                     \
    float M, m;                                                              \
    tree16(q0, q1, q2, q3, M, m);                                            \
    const bool u = M > vmax##S;                                              \
    vmax##S = u ? M : vmax##S;  gx##S = u ? gk : gx##S;                      \
    const bool v = m < vmin##S;                                              \
    vmin##S = v ? m : vmin##S;  gn##S = v ? gk : gn##S;                      \
  }

// ---- named A/B operand sets (rule-#20-safe: no runtime-indexed arrays) ----
#define DECL_SET(S)                                                          \
  float4 xa0##S, xa1##S, xa2##S, xa3##S, xb0##S, xb1##S, xb2##S, xb3##S;     \
  float4 wa0##S, wa1##S, wa2##S, wa3##S, wb0##S, wb1##S, wb2##S, wb3##S;

#define LOAD_SET(S, OFF)                                                     \
  {                                                                          \
    const int o_ = (OFF);                                                    \
    xa0##S = *reinterpret_cast<const float4*>(Xr0 + o_ + 0);                 \
    xa1##S = *reinterpret_cast<const float4*>(Xr0 + o_ + 4);                 \
    xa2##S = *reinterpret_cast<const float4*>(Xr0 + o_ + 8);                 \
    xa3##S = *reinterpret_cast<const float4*>(Xr0 + o_ + 12);                \
    xb0##S = *reinterpret_cast<const float4*>(Xr1 + o_ + 0);                 \
    xb1##S = *reinterpret_cast<const float4*>(Xr1 + o_ + 4);                 \
    xb2##S = *reinterpret_cast<const float4*>(Xr1 + o_ + 8);                 \
    xb3##S = *reinterpret_cast<const float4*>(Xr1 + o_ + 12);                \
    const float4* wap_ = reinterpret_cast<const float4*>(&sw[c0][o_]);       \
    wa0##S = wap_[0]; wa1##S = wap_[1]; wa2##S = wap_[2]; wa3##S = wap_[3];  \
    const float4* wbp_ = reinterpret_cast<const float4*>(&sw[c1][o_]);       \
    wb0##S = wbp_[0]; wb1##S = wbp_[1]; wb2##S = wbp_[2]; wb3##S = wbp_[3];  \
  }

#define COMP_SET(S, GK)                                                      \
  {                                                                          \
    const int gk = (GK);                                                     \
    CELL(00, xa0##S, xa1##S, xa2##S, xa3##S, wa0##S, wa1##S, wa2##S, wa3##S) \
    CELL(01, xa0##S, xa1##S, xa2##S, xa3##S, wb0##S, wb1##S, wb2##S, wb3##S) \
    CELL(10, xb0##S, xb1##S, xb2##S, xb3##S, wa0##S, wa1##S, wa2##S, wa3##S) \
    CELL(11, xb0##S, xb1##S, xb2##S, xb3##S, wb0##S, wb1##S, wb2##S, wb3##S) \
  }

// first k in [base, base+16) with x[k]*w[k] == tgt (descending selects ->
// first occurrence wins; +-0 compare-equal so fma(+0) targets match mul).
__device__ __forceinline__ int find_first_eq(const float* __restrict__ xr,
                                             const float* __restrict__ wr,
                                             float tgt, int base) {
  const float4 a0 = *(const float4*)(xr + 0),  a1 = *(const float4*)(xr + 4);
  const float4 a2 = *(const float4*)(xr + 8),  a3 = *(const float4*)(xr + 12);
  const float4 b0 = *(const float4*)(wr + 0),  b1 = *(const float4*)(wr + 4);
  const float4 b2 = *(const float4*)(wr + 8),  b3 = *(const float4*)(wr + 12);
  int idx = base;
  idx = (a3.w * b3.w == tgt) ? base + 15 : idx;
  idx = (a3.z * b3.z == tgt) ? base + 14 : idx;
  idx = (a3.y * b3.y == tgt) ? base + 13 : idx;
  idx = (a3.x * b3.x == tgt) ? base + 12 : idx;
  idx = (a2.w * b2.w == tgt) ? base + 11 : idx;
  idx = (a2.z * b2.z == tgt) ? base + 10 : idx;
  idx = (a2.y * b2.y == tgt) ? base +  9 : idx;
  idx = (a2.x * b2.x == tgt) ? base +  8 : idx;
  idx = (a1.w * b1.w == tgt) ? base +  7 : idx;
  idx = (a1.z * b1.z == tgt) ? base +  6 : idx;
  idx = (a1.y * b1.y == tgt) ? base +  5 : idx;
  idx = (a1.x * b1.x == tgt) ? base +  4 : idx;
  idx = (a0.w * b0.w == tgt) ? base +  3 : idx;
  idx = (a0.z * b0.z == tgt) ? base +  2 : idx;
  idx = (a0.y * b0.y == tgt) ? base +  1 : idx;
  idx = (a0.x * b0.x == tgt) ? base +  0 : idx;
  return idx;
}

__global__ __launch_bounds__(256, 2) void mam_kernel(
    const float* __restrict__ X,   // [NTOT][KTOT]
    const float* __restrict__ W,   // [MTOT][KTOT]
    const float* __restrict__ B,   // [MTOT]
    float* __restrict__ out)
{
  __shared__ float sw[BM][LDSPW];   // 66 KB: w tile for the ENTIRE K

  const int th = threadIdx.x;          // 0..255
  const int tn = th >> 4;              // 0..15
  const int tm = th & 15;              // 0..15
  const int n0 = blockIdx.y * BN;
  const int m0 = blockIdx.x * BM;
  const int r0 = tn, r1 = tn + 16;     // 2 output rows
  const int c0 = tm, c1 = tm + 16;     // 2 output cols

  // ---- stage w[32][512] once: 4096 float4, 256 threads -> 16 each ----
  #pragma unroll
  for (int j = 0; j < 16; ++j) {
    const int id  = th + 256 * j;      // 0..4095
    const int row = id >> 7;           // 0..31
    const int f   = id & 127;          // float4 slot within 512-float row
    *reinterpret_cast<float4*>(&sw[row][f * 4]) =
        *reinterpret_cast<const float4*>(&W[(m0 + row) * KTOT + f * 4]);
  }
  __syncthreads();   // the ONLY barrier

  const float* Xr0 = &X[(n0 + r0) * KTOT];
  const float* Xr1 = &X[(n0 + r1) * KTOT];

  float vmax00 = -INFINITY, vmax01 = -INFINITY, vmax10 = -INFINITY, vmax11 = -INFINITY;
  float vmin00 =  INFINITY, vmin01 =  INFINITY, vmin10 =  INFINITY, vmin11 =  INFINITY;
  int   gx00 = 0, gx01 = 0, gx10 = 0, gx11 = 0;
  int   gn00 = 0, gn01 = 0, gn10 = 0, gn11 = 0;

  DECL_SET(A)
  DECL_SET(B_)

  // ---- software-pipelined main loop: 32 groups, A/B sets, 1-deep prefetch ----
  LOAD_SET(A, 0)
  #pragma unroll
  for (int g = 0; g < 32; g += 2) {
    LOAD_SET(B_, (g + 1) * G)          // in flight during compute of A
    COMP_SET(A, g * G)
    if (g + 2 < 32) LOAD_SET(A, (g + 2) * G)   // in flight during compute of B
    COMP_SET(B_, (g + 1) * G)
  }

  // ---- windowed index recovery (L1/L2 hits), own 4 cells ----
  const float* Wc0 = &W[(m0 + c0) * KTOT];
  const float* Wc1 = &W[(m0 + c1) * KTOT];

  const int imax00 = find_first_eq(Xr0 + gx00, Wc0 + gx00, vmax00, gx00);
  const int imin00 = find_first_eq(Xr0 + gn00, Wc0 + gn00, vmin00, gn00);
  const int imax01 = find_first_eq(Xr0 + gx01, Wc1 + gx01, vmax01, gx01);
  const int imin01 = find_first_eq(Xr0 + gn01, Wc1 + gn01, vmin01, gn01);
  const int imax10 = find_first_eq(Xr1 + gx10, Wc0 + gx10, vmax10, gx10);
  const int imin10 = find_first_eq(Xr1 + gn10, Wc0 + gn10, vmin10, gn10);
  const int imax11 = find_first_eq(Xr1 + gx11, Wc1 + gx11, vmax11, gx11);
  const int imin11 = find_first_eq(Xr1 + gn11, Wc1 + gn11, vmin11, gn11);

  // ---- output ----
  float* Cout = out;
  float* AM   = out + NTOT * MTOT;
  float* AN   = AM + NTOT * MTOT;

  const float b0 = B[m0 + c0];
  const float b1 = B[m0 + c1];

  const int o00 = (n0 + r0) * MTOT + (m0 + c0);
  const int o01 = (n0 + r0) * MTOT + (m0 + c1);
  const int o10 = (n0 + r1) * MTOT + (m0 + c0);
  const int o11 = (n0 + r1) * MTOT + (m0 + c1);

  Cout[o00] = vmax00 + vmin00 + b0;  AM[o00] = (float)imax00;  AN[o00] = (float)imin00;
  Cout[o01] = vmax01 + vmin01 + b1;  AM[o01] = (float)imax01;  AN[o01] = (float)imin01;
  Cout[o10] = vmax10 + vmin10 + b0;  AM[o10] = (float)imax10;  AN[o10] = (float)imin10;
  Cout[o11] = vmax11 + vmin11 + b1;  AM[o11] = (float)imax11;  AN[o11] = (float)imin11;
}

extern "C" void kernel_launch(void* const* d_in, const int* in_sizes, int n_in,
                              void* d_out, int out_size, void* d_ws, size_t ws_size,
                              hipStream_t stream) {
  const float* X = (const float*)d_in[0];   // [8,128,512] -> [1024][512]
  const float* W = (const float*)d_in[1];   // [512][512]
  const float* B = (const float*)d_in[2];   // [512]
  float* out = (float*)d_out;

  dim3 grid(MTOT / BM, NTOT / BN);          // (16, 32) = 512 blocks, 256 thr
  mam_kernel<<<grid, dim3(256), 0, stream>>>(X, W, B, out);
}

// Round 17
// 40.006 us; speedup vs baseline: 2.3313x; 2.3313x over previous
//
#include <hip/hip_runtime.h>
#include <math.h>

// MAM "FullyConnected": C[n,m] = max_k(x[n,k]*w[m,k]) + min_k(...) + bias[m]
// plus argmax/argmin (first occurrence). N=1024, M=512, K=512, f32.
// d_out (read back as f32): C | argmax | argmin, each N*M.
//
// Round 17: wave-row restructure. Each wave owns 4 rows x 64 cols (lane =
// column). x is wave-uniform -> scalar (s_load/SGPR) via readfirstlane:
// zero VGPR cost, off the LDS+TA pipes. w in LDS, one column per lane;
// each ds_read_b128 feeds 4 cells (4x less LDS than R9, ~5us). No k-split,
// no merge. Live VGPRs ~70 (inside the compiler's proven 128 comfort zone).

constexpr int NTOT = 1024;
constexpr int MTOT = 512;
constexpr int KTOT = 512;
constexpr int BN = 16;        // rows per block (4 waves x 4 rows)
constexpr int BMC = 64;       // cols per block (= lanes)
constexpr int BK = 128;
constexpr int G  = 16;        // tournament group size
constexpr int LDSP = 132;     // row pad: 16B-aligned; lane-stride col reads bank-neutral

__device__ __forceinline__ float max3f(float a, float b, float c) {
  float d; asm("v_max3_f32 %0, %1, %2, %3" : "=v"(d) : "v"(a), "v"(b), "v"(c)); return d;
}
__device__ __forceinline__ float min3f(float a, float b, float c) {
  float d; asm("v_min3_f32 %0, %1, %2, %3" : "=v"(d) : "v"(a), "v"(b), "v"(c)); return d;
}

__device__ __forceinline__ void tree16(const float4& q0, const float4& q1,
                                       const float4& q2, const float4& q3,
                                       float& M, float& m) {
  M = fmaxf(max3f(max3f(q0.x, q0.y, q0.z), max3f(q0.w, q1.x, q1.y),
                  max3f(q1.z, q1.w, q2.x)),
            max3f(max3f(q2.y, q2.z, q2.w), q3.x, max3f(q3.y, q3.z, q3.w)));
  m = fminf(min3f(min3f(q0.x, q0.y, q0.z), min3f(q0.w, q1.x, q1.y),
                  min3f(q1.z, q1.w, q2.x)),
            min3f(min3f(q2.y, q2.z, q2.w), q3.x, min3f(q3.y, q3.z, q3.w)));
}

// one row-cell: 16 products (scalar x * vector w), value trees, group update.
// strict > / < keeps the FIRST group attaining the extremum.
#define ROW(J)                                                               \
  {                                                                          \
    const float* Xr = X##J;                                                  \
    const float4 q0 = make_float4(Xr[gk +  0] * w0.x, Xr[gk +  1] * w0.y,    \
                                  Xr[gk +  2] * w0.z, Xr[gk +  3] * w0.w);   \
    const float4 q1 = make_float4(Xr[gk +  4] * w1.x, Xr[gk +  5] * w1.y,    \
                                  Xr[gk +  6] * w1.z, Xr[gk +  7] * w1.w);   \
    const float4 q2 = make_float4(Xr[gk +  8] * w2.x, Xr[gk +  9] * w2.y,    \
                                  Xr[gk + 10] * w2.z, Xr[gk + 11] * w2.w);   \
    const float4 q3 = make_float4(Xr[gk + 12] * w3.x, Xr[gk + 13] * w3.y,    \
                                  Xr[gk + 14] * w3.z, Xr[gk + 15] * w3.w);   \
    float M, mn;                                                             \
    tree16(q0, q1, q2, q3, M, mn);                                           \
    const bool u = M > vmax##J;                                              \
    vmax##J = u ? M : vmax##J;  gx##J = u ? gk : gx##J;                      \
    const bool v = mn < vmin##J;                                             \
    vmin##J = v ? mn : vmin##J;  gn##J = v ? gk : gn##J;                     \
  }

// first k in [base, base+16) with x[k]*w[k] == tgt (descending selects ->
// first occurrence wins).
__device__ __forceinline__ int find_first_eq(const float* __restrict__ xr,
                                             const float* __restrict__ wr,
                                             float tgt, int base) {
  const float4 a0 = *(const float4*)(xr + 0),  a1 = *(const float4*)(xr + 4);
  const float4 a2 = *(const float4*)(xr + 8),  a3 = *(const float4*)(xr + 12);
  const float4 b0 = *(const float4*)(wr + 0),  b1 = *(const float4*)(wr + 4);
  const float4 b2 = *(const float4*)(wr + 8),  b3 = *(const float4*)(wr + 12);
  int idx = base;
  idx = (a3.w * b3.w == tgt) ? base + 15 : idx;
  idx = (a3.z * b3.z == tgt) ? base + 14 : idx;
  idx = (a3.y * b3.y == tgt) ? base + 13 : idx;
  idx = (a3.x * b3.x == tgt) ? base + 12 : idx;
  idx = (a2.w * b2.w == tgt) ? base + 11 : idx;
  idx = (a2.z * b2.z == tgt) ? base + 10 : idx;
  idx = (a2.y * b2.y == tgt) ? base +  9 : idx;
  idx = (a2.x * b2.x == tgt) ? base +  8 : idx;
  idx = (a1.w * b1.w == tgt) ? base +  7 : idx;
  idx = (a1.z * b1.z == tgt) ? base +  6 : idx;
  idx = (a1.y * b1.y == tgt) ? base +  5 : idx;
  idx = (a1.x * b1.x == tgt) ? base +  4 : idx;
  idx = (a0.w * b0.w == tgt) ? base +  3 : idx;
  idx = (a0.z * b0.z == tgt) ? base +  2 : idx;
  idx = (a0.y * b0.y == tgt) ? base +  1 : idx;
  idx = (a0.x * b0.x == tgt) ? base +  0 : idx;
  return idx;
}

__global__ __launch_bounds__(256, 2) void mam_kernel(
    const float* __restrict__ X,   // [NTOT][KTOT]
    const float* __restrict__ W,   // [MTOT][KTOT]
    const float* __restrict__ B,   // [MTOT]
    float* __restrict__ out)
{
  __shared__ float sw[BMC][LDSP];   // 33.8 KB: w tile, one column per lane

  const int th   = threadIdx.x;        // 0..255
  const int lane = th & 63;            // column within block tile
  // wave id, forced scalar so x addressing is provably wave-uniform
  const int wid  = __builtin_amdgcn_readfirstlane(th >> 6);   // 0..3
  const int n0 = blockIdx.y * BN;
  const int m0 = blockIdx.x * BMC;
  const int nb = n0 + wid * 4;         // this wave's 4 rows
  const int m  = m0 + lane;

  const float* X0 = &X[(nb + 0) * KTOT];
  const float* X1 = &X[(nb + 1) * KTOT];
  const float* X2 = &X[(nb + 2) * KTOT];
  const float* X3 = &X[(nb + 3) * KTOT];

  float vmax0 = -INFINITY, vmax1 = -INFINITY, vmax2 = -INFINITY, vmax3 = -INFINITY;
  float vmin0 =  INFINITY, vmin1 =  INFINITY, vmin2 =  INFINITY, vmin3 =  INFINITY;
  int   gx0 = 0, gx1 = 0, gx2 = 0, gx3 = 0;
  int   gn0 = 0, gn1 = 0, gn2 = 0, gn3 = 0;

  #pragma unroll 1
  for (int kc = 0; kc < KTOT; kc += BK) {
    __syncthreads();  // protect LDS from previous iteration's readers
    // stage w[64][128]: 2048 float4, 256 threads -> 8 each
    #pragma unroll
    for (int j = 0; j < 8; ++j) {
      const int id = th + 256 * j;     // 0..2047
      const int r  = id >> 5;          // 0..63
      const int f  = id & 31;
      *reinterpret_cast<float4*>(&sw[r][f * 4]) =
          *reinterpret_cast<const float4*>(&W[(m0 + r) * KTOT + kc + f * 4]);
    }
    __syncthreads();

    #pragma unroll
    for (int g = 0; g < BK / G; ++g) {  // 8 groups of 16 k
      const int off = g * G;
      const int gk  = kc + off;         // wave-uniform
      // w: this lane's column, 4x ds_read_b128 feeding all 4 cells
      const float4* wp = reinterpret_cast<const float4*>(&sw[lane][off]);
      const float4 w0 = wp[0], w1 = wp[1], w2 = wp[2], w3 = wp[3];
      // x: wave-uniform scalar loads (SMEM pipe, SGPRs)
      ROW(0)
      ROW(1)
      ROW(2)
      ROW(3)
    }
  }

  // ---- windowed index recovery (L1/L2 hits), own 4 cells ----
  const float* Wm = &W[m * KTOT];
  const int imax0 = find_first_eq(X0 + gx0, Wm + gx0, vmax0, gx0);
  const int imin0 = find_first_eq(X0 + gn0, Wm + gn0, vmin0, gn0);
  const int imax1 = find_first_eq(X1 + gx1, Wm + gx1, vmax1, gx1);
  const int imin1 = find_first_eq(X1 + gn1, Wm + gn1, vmin1, gn1);
  const int imax2 = find_first_eq(X2 + gx2, Wm + gx2, vmax2, gx2);
  const int imin2 = find_first_eq(X2 + gn2, Wm + gn2, vmin2, gn2);
  const int imax3 = find_first_eq(X3 + gx3, Wm + gx3, vmax3, gx3);
  const int imin3 = find_first_eq(X3 + gn3, Wm + gn3, vmin3, gn3);

  // ---- output (coalesced across lanes) ----
  float* Cout = out;
  float* AM   = out + NTOT * MTOT;
  float* AN   = AM + NTOT * MTOT;
  const float bm = B[m];

  const int o0 = (nb + 0) * MTOT + m;
  const int o1 = (nb + 1) * MTOT + m;
  const int o2 = (nb + 2) * MTOT + m;
  const int o3 = (nb + 3) * MTOT + m;

  Cout[o0] = vmax0 + vmin0 + bm;  AM[o0] = (float)imax0;  AN[o0] = (float)imin0;
  Cout[o1] = vmax1 + vmin1 + bm;  AM[o1] = (float)imax1;  AN[o1] = (float)imin1;
  Cout[o2] = vmax2 + vmin2 + bm;  AM[o2] = (float)imax2;  AN[o2] = (float)imin2;
  Cout[o3] = vmax3 + vmin3 + bm;  AM[o3] = (float)imax3;  AN[o3] = (float)imin3;
}

extern "C" void kernel_launch(void* const* d_in, const int* in_sizes, int n_in,
                              void* d_out, int out_size, void* d_ws, size_t ws_size,
                              hipStream_t stream) {
  const float* X = (const float*)d_in[0];   // [8,128,512] -> [1024][512]
  const float* W = (const float*)d_in[1];   // [512][512]
  const float* B = (const float*)d_in[2];   // [512]
  float* out = (float*)d_out;

  dim3 grid(MTOT / BMC, NTOT / BN);         // (8, 64) = 512 blocks, 256 thr
  mam_kernel<<<grid, dim3(256), 0, stream>>>(X, W, B, out);
}